// Round 1
// baseline (781.025 us; speedup 1.0000x reference)
//
#include <hip/hip_runtime.h>
#include <stdint.h>

#define EPSV 1e-5f

using floatx4 = __attribute__((ext_vector_type(4))) float;
using short8  = __attribute__((ext_vector_type(8))) short;

// async global->LDS 16B DMA: data lands at ldsbase + lane*16
#define GLD(gp, lp) __builtin_amdgcn_global_load_lds( \
    (const __attribute__((address_space(1))) void*)(gp), \
    (__attribute__((address_space(3))) void*)(lp), 16, 0, 0)

__device__ __forceinline__ unsigned short f2bf(float f) {
  union { float f; unsigned int u; } x; x.f = f;
  unsigned int r = x.u + 0x7fffu + ((x.u >> 16) & 1u);  // RNE
  return (unsigned short)(r >> 16);
}

// ---------------------------------------------------------------------------
// Upsample (align-corners bilinear 32->64) + alpha*xm fuse, write bf16 NHWC
// into zero-padded [8][66][66][512] buffer (interior only; border pre-zeroed).
// tid order: cin innermost -> coalesced bf16 writes; reads scattered but L2/L3
// resident (xt 8.4MB, xm 67MB < 256MB LLC).
// ---------------------------------------------------------------------------
__global__ __launch_bounds__(256) void fuse_upsample_kernel(
    const float* __restrict__ xt, const float* __restrict__ xm,
    const float* __restrict__ alpha, unsigned short* __restrict__ Xp) {
  int idx = blockIdx.x * 256 + threadIdx.x;   // ((b*64+y)*64+x)*512 + c
  int c = idx & 511;
  int x = (idx >> 9) & 63;
  int y = (idx >> 15) & 63;
  int b = idx >> 21;
  float a = alpha[0];
  float xmv = xm[(((b << 9) + c) << 12) + (y << 6) + x];
  float fy = y * (31.0f / 63.0f);
  float fx = x * (31.0f / 63.0f);
  int y0 = (int)fy, x0 = (int)fx;
  float wy = fy - (float)y0, wx = fx - (float)x0;
  int y1 = min(y0 + 1, 31), x1 = min(x0 + 1, 31);
  const float* tp = xt + (((b << 9) + c) << 10);
  float v00 = tp[(y0 << 5) + x0], v01 = tp[(y0 << 5) + x1];
  float v10 = tp[(y1 << 5) + x0], v11 = tp[(y1 << 5) + x1];
  float top = v00 * (1.0f - wx) + v01 * wx;
  float bot = v10 * (1.0f - wx) + v11 * wx;
  float up  = top * (1.0f - wy) + bot * wy;
  Xp[((b * 66 + y + 1) * 66 + (x + 1)) * 512 + c] = f2bf(up + a * xmv);
}

// ---------------------------------------------------------------------------
// Repack weights OIHW fp32 -> [tap][cout][cin] bf16 (tap = ky*3+kx)
// ---------------------------------------------------------------------------
template <int COUT>
__global__ __launch_bounds__(256) void prep_w_kernel(
    const float* __restrict__ w, unsigned short* __restrict__ Wg) {
  int idx = blockIdx.x * 256 + threadIdx.x;   // (tap*COUT + o)*512 + i
  int i = idx & 511;
  int o = (idx >> 9) % COUT;
  int tap = idx / (COUT * 512);
  Wg[idx] = f2bf(w[(o * 512 + i) * 9 + tap]);
}

// ---------------------------------------------------------------------------
// Implicit-GEMM 3x3 conv + BN + ReLU.
// Input : padded NHWC bf16 [8][66][66][512]
// Weights: [9][COUT][512] bf16
// Block: 128 pixels x 128 couts; 4 waves (2x2), each 64x64 via 16 MFMAs/Kstep.
// K = 9 taps x 512 cin, BK=32 (144 steps). LDS tiles [128][32] bf16, staged
// with global_load_lds dwordx4 (2 chunks/thread/tile).
// ---------------------------------------------------------------------------
template <int COUT, bool FINAL>
__global__ __launch_bounds__(256) void conv3x3_kernel(
    const unsigned short* __restrict__ Xp, const unsigned short* __restrict__ Wg,
    const float* __restrict__ gamma, const float* __restrict__ beta,
    const float* __restrict__ mean, const float* __restrict__ var,
    unsigned short* __restrict__ OutPad, float* __restrict__ OutF) {
  static_assert(COUT % 128 == 0, "");
  constexpr int NCT = COUT / 128;
  __shared__ unsigned short At[128 * 32];
  __shared__ unsigned short Bt[128 * 32];

  const int tid = threadIdx.x;
  const int ptile = (int)blockIdx.x / NCT;
  const int ctile = (int)blockIdx.x % NCT;
  const int p0 = ptile * 128;
  const int w = tid >> 6;
  const int lane = tid & 63;

  // ---- staging addresses (this thread owns chunks tid and tid+256 per tile)
  const int q  = tid & 3;        // 16B chunk within a 64B row
  const int r0 = tid >> 2;       // row 0..63 ; second chunk row = r0+64
  int a0, a1;
  {
    int p = p0 + r0;
    int pb = p >> 12, py = (p >> 6) & 63, px = p & 63;
    a0 = ((pb * 66 + py + 1) * 66 + (px + 1)) * 512 + q * 8;
    p = p0 + r0 + 64;
    pb = p >> 12; py = (p >> 6) & 63; px = p & 63;
    a1 = ((pb * 66 + py + 1) * 66 + (px + 1)) * 512 + q * 8;
  }
  const int wb0 = (ctile * 128 + r0) * 512 + q * 8;
  const int wb1 = wb0 + 64 * 512;

  // wave-uniform LDS DMA bases (lane data lands at base + lane*16B)
  unsigned short* At0 = At + w * 512;
  unsigned short* At1 = At + 2048 + w * 512;
  unsigned short* Bt0 = Bt + w * 512;
  unsigned short* Bt1 = Bt + 2048 + w * 512;

  // ---- fragment read setup
  const int fi = lane & 15;      // row within 16-subtile / output col
  const int kc = lane >> 4;      // k-octet
  const int wm = w >> 1, wn = w & 1;
  const unsigned short* Ar = At + (wm * 64 + fi) * 32 + kc * 8;
  const unsigned short* Br = Bt + (wn * 64 + fi) * 32 + kc * 8;

  floatx4 acc[4][4] = {};

  for (int s = 0; s < 144; ++s) {
    const int tap = s >> 4;
    const int cs  = (s & 15) << 5;
    const int dy = tap / 3 - 1;
    const int dx = tap % 3 - 1;
    const int ao = (dy * 66 + dx) * 512 + cs;
    const int wo = tap * COUT * 512 + cs;

    GLD(Xp + a0 + ao, At0);
    GLD(Xp + a1 + ao, At1);
    GLD(Wg + wb0 + wo, Bt0);
    GLD(Wg + wb1 + wo, Bt1);
    __syncthreads();   // drains vmcnt -> DMA complete

    short8 af[4], bfr[4];
#pragma unroll
    for (int mi = 0; mi < 4; ++mi) af[mi] = *(const short8*)(Ar + mi * 16 * 32);
#pragma unroll
    for (int ni = 0; ni < 4; ++ni) bfr[ni] = *(const short8*)(Br + ni * 16 * 32);
#pragma unroll
    for (int mi = 0; mi < 4; ++mi)
#pragma unroll
      for (int ni = 0; ni < 4; ++ni)
        acc[mi][ni] = __builtin_amdgcn_mfma_f32_16x16x32_bf16(
            af[mi], bfr[ni], acc[mi][ni], 0, 0, 0);
    __syncthreads();   // protect LDS before next stage
  }

  // ---- epilogue: BN + ReLU
  // C/D layout: col = lane&15 (=cout), row = (lane>>4)*4 + reg (=pixel)
#pragma unroll
  for (int ni = 0; ni < 4; ++ni) {
    const int co = ctile * 128 + wn * 64 + ni * 16 + fi;
    const float sc = gamma[co] / sqrtf(var[co] + EPSV);
    const float sh = beta[co] - mean[co] * sc;
#pragma unroll
    for (int mi = 0; mi < 4; ++mi) {
      const int p = p0 + wm * 64 + mi * 16 + kc * 4;  // 4 consecutive pixels
      const int pb = p >> 12;
      const int prem = p & 4095;
      if constexpr (FINAL) {
        floatx4 o;
#pragma unroll
        for (int r = 0; r < 4; ++r) o[r] = fmaxf(acc[mi][ni][r] * sc + sh, 0.0f);
        *(floatx4*)(OutF + ((pb * COUT + co) << 12) + prem) = o;  // NCHW fp32
      } else {
        const int py = prem >> 6, px = prem & 63;
        unsigned short* dst = OutPad + ((pb * 66 + py + 1) * 66 + (px + 1)) * 512 + co;
#pragma unroll
        for (int r = 0; r < 4; ++r)
          dst[r * 512] = f2bf(fmaxf(acc[mi][ni][r] * sc + sh, 0.0f));
      }
    }
  }
}

// ---------------------------------------------------------------------------
// workspace layout (bytes):
//   Xp0 : 0          .. 35684352   (8*66*66*512 bf16)
//   Xp1 : 35684352   .. 71368704
//   Wg0 : 71368704   .. 76087296   (9*512*512 bf16)
//   Wg1 : 76087296   .. 78446592   (9*256*512 bf16)
// ---------------------------------------------------------------------------
extern "C" void kernel_launch(void* const* d_in, const int* in_sizes, int n_in,
                              void* d_out, int out_size, void* d_ws, size_t ws_size,
                              hipStream_t stream) {
  const float* xt    = (const float*)d_in[0];
  const float* xm    = (const float*)d_in[1];
  const float* alpha = (const float*)d_in[3];
  const float* w0    = (const float*)d_in[4];
  const float* g0    = (const float*)d_in[5];
  const float* b0    = (const float*)d_in[6];
  const float* m0    = (const float*)d_in[7];
  const float* v0    = (const float*)d_in[8];
  const float* w1    = (const float*)d_in[9];
  const float* g1    = (const float*)d_in[10];
  const float* b1    = (const float*)d_in[11];
  const float* m1    = (const float*)d_in[12];
  const float* v1    = (const float*)d_in[13];
  float* out = (float*)d_out;

  char* ws = (char*)d_ws;
  unsigned short* Xp0 = (unsigned short*)(ws);
  unsigned short* Xp1 = (unsigned short*)(ws + 35684352);
  unsigned short* Wg0 = (unsigned short*)(ws + 2 * 35684352);
  unsigned short* Wg1 = (unsigned short*)(ws + 2 * 35684352 + 4718592);

  hipMemsetAsync(Xp0, 0, 35684352, stream);
  hipMemsetAsync(Xp1, 0, 35684352, stream);
  prep_w_kernel<512><<<9216, 256, 0, stream>>>(w0, Wg0);
  prep_w_kernel<256><<<4608, 256, 0, stream>>>(w1, Wg1);
  fuse_upsample_kernel<<<65536, 256, 0, stream>>>(xt, xm, alpha, Xp0);
  conv3x3_kernel<512, false><<<1024, 256, 0, stream>>>(Xp0, Wg0, g0, b0, m0, v0, Xp1, nullptr);
  conv3x3_kernel<256, true><<<512, 256, 0, stream>>>(Xp1, Wg1, g1, b1, m1, v1, nullptr, out);
}

// Round 2
// 713.247 us; speedup vs baseline: 1.0950x; 1.0950x over previous
//
#include <hip/hip_runtime.h>
#include <stdint.h>

#define EPSV 1e-5f

using floatx4 = __attribute__((ext_vector_type(4))) float;
using short8  = __attribute__((ext_vector_type(8))) short;

// async global->LDS 16B DMA: data lands at ldsbase + lane*16
#define GLD(gp, lp) __builtin_amdgcn_global_load_lds( \
    (const __attribute__((address_space(1))) void*)(gp), \
    (__attribute__((address_space(3))) void*)(lp), 16, 0, 0)

__device__ __forceinline__ unsigned short f2bf(float f) {
  union { float f; unsigned int u; } x; x.f = f;
  unsigned int r = x.u + 0x7fffu + ((x.u >> 16) & 1u);  // RNE
  return (unsigned short)(r >> 16);
}

// ---------------------------------------------------------------------------
// Zero the halo border of both padded NHWC buffers (2.13 MB each vs 35.7 MB
// full memset). 260 border pixels per 66x66 image; 512 ch; 8 batches.
// ---------------------------------------------------------------------------
__global__ __launch_bounds__(256) void border_zero_kernel(
    unsigned short* __restrict__ Xp0, unsigned short* __restrict__ Xp1) {
  int idx = blockIdx.x * 256 + threadIdx.x;   // 520 blocks * 256 = 133120
  int ck = idx & 63;            // 8-ch chunk
  int rest = idx >> 6;
  int k = rest % 260;           // border pixel id
  int b = rest / 260;
  int py, px;
  if (k < 66)       { py = 0;  px = k; }
  else if (k < 132) { py = 65; px = k - 66; }
  else { int k2 = k - 132; py = 1 + (k2 >> 1); px = (k2 & 1) ? 65 : 0; }
  long off = ((long)(b * 66 + py) * 66 + px) * 512 + ck * 8;
  short8 z = {};
  *(short8*)(Xp0 + off) = z;
  *(short8*)(Xp1 + off) = z;
}

// ---------------------------------------------------------------------------
// Upsample (align-corners bilinear 32->64) + alpha*xm fuse -> bf16 NHWC pad.
// Tile per block: one (b, y) output row x 64 x x 32 channels, transposed
// through LDS so BOTH the NCHW fp32 reads and NHWC bf16 writes coalesce.
// ---------------------------------------------------------------------------
__global__ __launch_bounds__(256) void fuse_upsample_kernel(
    const float* __restrict__ xt, const float* __restrict__ xm,
    const float* __restrict__ alpha, unsigned short* __restrict__ Xp) {
  __shared__ float sm[32 * 66];        // xm tile [c][x], pad 66
  __shared__ float st[2 * 32 * 34];    // xt rows [h][c][x0..31], pad 34

  const int tid = threadIdx.x;
  const int ct = blockIdx.x & 15;          // channel tile (32 ch)
  const int y  = (blockIdx.x >> 4) & 63;
  const int b  = blockIdx.x >> 10;
  const int c0 = ct * 32;

  const float fy = y * (31.0f / 63.0f);
  const int y0 = (int)fy;
  const float wy = fy - (float)y0;
  const int y1 = min(y0 + 1, 31);

  // phase 1: xm tile, lane = x (coalesced 256B rows)
  {
    const int cb = (tid >> 6) * 8;
    const int xi = tid & 63;
#pragma unroll
    for (int j = 0; j < 8; ++j) {
      int c = cb + j;
      sm[c * 66 + xi] = xm[(((b << 9) + c0 + c) << 12) + (y << 6) + xi];
    }
  }
  // phase 2: xt rows y0,y1 (32 x-contiguous floats per (h,c) -> coalesced)
#pragma unroll
  for (int j = 0; j < 8; ++j) {
    int idx = j * 256 + tid;
    int xi = idx & 31, cc = (idx >> 5) & 31, h = idx >> 10;
    int yr = h ? y1 : y0;
    st[h * 1088 + cc * 34 + xi] =
        xt[(((b << 9) + c0 + cc) << 10) + (yr << 5) + xi];
  }
  __syncthreads();

  // phase 3: interpolate + fuse, write 16B bf16 chunks (coalesced NHWC)
  const float a = alpha[0];
  const int xo = tid >> 2;
  const float fx = xo * (31.0f / 63.0f);
  const int x0 = (int)fx;
  const float wx = fx - (float)x0;
  const int x1 = min(x0 + 1, 31);
  short8 ov;
#pragma unroll
  for (int j = 0; j < 8; ++j) {
    int c = (tid & 3) * 8 + j;
    float t0 = st[c * 34 + x0], t1 = st[c * 34 + x1];
    float u0 = st[1088 + c * 34 + x0], u1 = st[1088 + c * 34 + x1];
    float top = t0 * (1.0f - wx) + t1 * wx;
    float bot = u0 * (1.0f - wx) + u1 * wx;
    float up = top * (1.0f - wy) + bot * wy;
    float val = up + a * sm[c * 66 + xo];
    ov[j] = (short)f2bf(val);
  }
  *(short8*)(Xp + ((long)(b * 66 + y + 1) * 66 + xo + 1) * 512 + c0 +
             (tid & 3) * 8) = ov;
}

// ---------------------------------------------------------------------------
// Repack weights OIHW fp32 -> [tap][cout][cin] bf16, transposed through LDS
// so global reads are fully coalesced. One block per output channel o.
// ---------------------------------------------------------------------------
template <int COUT>
__global__ __launch_bounds__(256) void prep_w_kernel(
    const float* __restrict__ w, unsigned short* __restrict__ Wg) {
  __shared__ unsigned short l[4608];   // [tap][cin]
  const int o = blockIdx.x, t = threadIdx.x;
  const float* src = w + o * 4608;
#pragma unroll
  for (int j = 0; j < 18; ++j) {
    int idx = j * 256 + t;             // = i*9 + tap
    l[(idx % 9) * 512 + idx / 9] = f2bf(src[idx]);
  }
  __syncthreads();
#pragma unroll
  for (int tap = 0; tap < 9; ++tap)
    *(unsigned int*)(Wg + ((tap * COUT + o) << 9) + 2 * t) =
        *(const unsigned int*)(l + (tap << 9) + 2 * t);
}

// ---------------------------------------------------------------------------
// Implicit-GEMM 3x3 conv + BN + ReLU.
// Input : padded NHWC bf16 [8][66][66][512] ; weights [9][COUT][512] bf16
// Block: 128 pixels x 128 couts, 4 waves (2x2), 64x64 each, 16x16x32 MFMA.
// BK=64 (72 K-steps). LDS k-major: [8 kchunk][128 row][8 bf16] per tile ->
// fragment ds_read_b128 phases hit distinct bank quads (conflict-free).
// Staged via global_load_lds width=16: wave w owns kchunks {2w, 2w+1}.
// ---------------------------------------------------------------------------
template <int COUT, bool FINAL>
__global__ __launch_bounds__(256) void conv3x3_kernel(
    const unsigned short* __restrict__ Xp, const unsigned short* __restrict__ Wg,
    const float* __restrict__ gamma, const float* __restrict__ beta,
    const float* __restrict__ mean, const float* __restrict__ var,
    unsigned short* __restrict__ OutPad, float* __restrict__ OutF) {
  static_assert(COUT % 128 == 0, "");
  constexpr int NCT = COUT / 128;
  __shared__ unsigned short At[8192];  // 16 KB, [q][r][8]
  __shared__ unsigned short Bt[8192];

  const int tid = threadIdx.x;
  const int ptile = (int)blockIdx.x / NCT;
  const int ctile = (int)blockIdx.x % NCT;
  const int p0 = ptile * 128;
  const int w = tid >> 6;
  const int lane = tid & 63;
  const int q0 = w * 2;

  // ---- staging bases (lane -> row; wave -> kchunk pair)
  int apix0, apix1, brow0, brow1;
  {
    int p = p0 + lane;
    int pb = p >> 12, py = (p >> 6) & 63, px = p & 63;
    apix0 = ((pb * 66 + py + 1) * 66 + px + 1) * 512 + q0 * 8;
    p = p0 + 64 + lane;
    pb = p >> 12; py = (p >> 6) & 63; px = p & 63;
    apix1 = ((pb * 66 + py + 1) * 66 + px + 1) * 512 + q0 * 8;
    brow0 = (ctile * 128 + lane) * 512 + q0 * 8;
    brow1 = brow0 + 64 * 512;
  }
  unsigned short* Alds = At + q0 * 1024;   // regions: q*1024 + h*512 (elems)
  unsigned short* Blds = Bt + q0 * 1024;

  // ---- fragment read setup
  const int fi = lane & 15;
  const int kc = lane >> 4;
  const int wm = w >> 1, wn = w & 1;
  const unsigned short* Abase = At + kc * 1024 + (wm * 64 + fi) * 8;
  const unsigned short* Bbase = Bt + kc * 1024 + (wn * 64 + fi) * 8;

  floatx4 acc[4][4] = {};

  for (int s = 0; s < 72; ++s) {
    const int tap = s >> 3;
    const int cs  = (s & 7) << 6;
    const int dy = tap / 3 - 1;
    const int dx = tap % 3 - 1;
    const int aoff = (dy * 66 + dx) * 512 + cs;
    const int woff = tap * COUT * 512 + cs;

    GLD(Xp + apix0 + aoff,     Alds);
    GLD(Xp + apix1 + aoff,     Alds + 512);
    GLD(Xp + apix0 + aoff + 8, Alds + 1024);
    GLD(Xp + apix1 + aoff + 8, Alds + 1536);
    GLD(Wg + brow0 + woff,     Blds);
    GLD(Wg + brow1 + woff,     Blds + 512);
    GLD(Wg + brow0 + woff + 8, Blds + 1024);
    GLD(Wg + brow1 + woff + 8, Blds + 1536);
    __syncthreads();   // drains vmcnt -> DMA complete

#pragma unroll
    for (int t = 0; t < 2; ++t) {
      short8 af[4], bfr[4];
#pragma unroll
      for (int mi = 0; mi < 4; ++mi)
        af[mi] = *(const short8*)(Abase + t * 4096 + mi * 128);
#pragma unroll
      for (int ni = 0; ni < 4; ++ni)
        bfr[ni] = *(const short8*)(Bbase + t * 4096 + ni * 128);
#pragma unroll
      for (int mi = 0; mi < 4; ++mi)
#pragma unroll
        for (int ni = 0; ni < 4; ++ni)
          acc[mi][ni] = __builtin_amdgcn_mfma_f32_16x16x32_bf16(
              af[mi], bfr[ni], acc[mi][ni], 0, 0, 0);
    }
    __syncthreads();   // protect LDS before next stage
  }

  // ---- epilogue: BN + ReLU
  // C/D layout: col = lane&15 (=cout), row = (lane>>4)*4 + reg (=pixel)
#pragma unroll
  for (int ni = 0; ni < 4; ++ni) {
    const int co = ctile * 128 + wn * 64 + ni * 16 + fi;
    const float sc = gamma[co] / sqrtf(var[co] + EPSV);
    const float sh = beta[co] - mean[co] * sc;
#pragma unroll
    for (int mi = 0; mi < 4; ++mi) {
      const int p = p0 + wm * 64 + mi * 16 + kc * 4;  // 4 consecutive pixels
      const int pb = p >> 12;
      const int prem = p & 4095;
      if constexpr (FINAL) {
        floatx4 o;
#pragma unroll
        for (int r = 0; r < 4; ++r) o[r] = fmaxf(acc[mi][ni][r] * sc + sh, 0.0f);
        *(floatx4*)(OutF + ((pb * COUT + co) << 12) + prem) = o;  // NCHW fp32
      } else {
        const int py = prem >> 6, px = prem & 63;
        unsigned short* dst = OutPad + ((pb * 66 + py + 1) * 66 + (px + 1)) * 512 + co;
#pragma unroll
        for (int r = 0; r < 4; ++r)
          dst[r * 512] = f2bf(fmaxf(acc[mi][ni][r] * sc + sh, 0.0f));
      }
    }
  }
}

// ---------------------------------------------------------------------------
// workspace layout (bytes):
//   Xp0 : 0          .. 35684352   (8*66*66*512 bf16)
//   Xp1 : 35684352   .. 71368704
//   Wg0 : 71368704   .. 76087296   (9*512*512 bf16)
//   Wg1 : 76087296   .. 78446592   (9*256*512 bf16)
// ---------------------------------------------------------------------------
extern "C" void kernel_launch(void* const* d_in, const int* in_sizes, int n_in,
                              void* d_out, int out_size, void* d_ws, size_t ws_size,
                              hipStream_t stream) {
  const float* xt    = (const float*)d_in[0];
  const float* xm    = (const float*)d_in[1];
  const float* alpha = (const float*)d_in[3];
  const float* w0    = (const float*)d_in[4];
  const float* g0    = (const float*)d_in[5];
  const float* b0    = (const float*)d_in[6];
  const float* m0    = (const float*)d_in[7];
  const float* v0    = (const float*)d_in[8];
  const float* w1    = (const float*)d_in[9];
  const float* g1    = (const float*)d_in[10];
  const float* b1    = (const float*)d_in[11];
  const float* m1    = (const float*)d_in[12];
  const float* v1    = (const float*)d_in[13];
  float* out = (float*)d_out;

  char* ws = (char*)d_ws;
  unsigned short* Xp0 = (unsigned short*)(ws);
  unsigned short* Xp1 = (unsigned short*)(ws + 35684352);
  unsigned short* Wg0 = (unsigned short*)(ws + 2 * 35684352);
  unsigned short* Wg1 = (unsigned short*)(ws + 2 * 35684352 + 4718592);

  border_zero_kernel<<<520, 256, 0, stream>>>(Xp0, Xp1);
  prep_w_kernel<512><<<512, 256, 0, stream>>>(w0, Wg0);
  prep_w_kernel<256><<<256, 256, 0, stream>>>(w1, Wg1);
  fuse_upsample_kernel<<<8192, 256, 0, stream>>>(xt, xm, alpha, Xp0);
  conv3x3_kernel<512, false><<<1024, 256, 0, stream>>>(Xp0, Wg0, g0, b0, m0, v0, Xp1, nullptr);
  conv3x3_kernel<256, true><<<512, 256, 0, stream>>>(Xp1, Wg1, g1, b1, m1, v1, nullptr, out);
}

// Round 3
// 567.704 us; speedup vs baseline: 1.3758x; 1.2564x over previous
//
#include <hip/hip_runtime.h>
#include <stdint.h>

#define EPSV 1e-5f

// c8-chunked activation layout: elem = cc*278784 + ((b*66+y)*66+x)*8 + (c&7)
#define CPLANE 278784   // 8*66*66*8 elems per channel-chunk plane

using floatx4 = __attribute__((ext_vector_type(4))) float;
using short8  = __attribute__((ext_vector_type(8))) short;

// async global->LDS 16B DMA: data lands at ldsbase + lane*16
#define GLD(gp, lp) __builtin_amdgcn_global_load_lds( \
    (const __attribute__((address_space(1))) void*)(gp), \
    (__attribute__((address_space(3))) void*)(lp), 16, 0, 0)

__device__ __forceinline__ unsigned short f2bf(float f) {
  union { float f; unsigned int u; } x; x.f = f;
  unsigned int r = x.u + 0x7fffu + ((x.u >> 16) & 1u);  // RNE
  return (unsigned short)(r >> 16);
}

// ---------------------------------------------------------------------------
// Zero the halo border of both padded c8 buffers (2.13 MB each).
// lane-inner = border-pixel index -> contiguous 16B chunks along rows.
// ---------------------------------------------------------------------------
__global__ __launch_bounds__(256) void border_zero_kernel(
    unsigned short* __restrict__ Xp0, unsigned short* __restrict__ Xp1) {
  int idx = blockIdx.x * 256 + threadIdx.x;   // 520*256 = 133120 = 8*64*260
  int k = idx % 260;
  int rest = idx / 260;
  int cc = rest & 63;
  int b = rest >> 6;
  int py, px;
  if (k < 66)       { py = 0;  px = k; }
  else if (k < 132) { py = 65; px = k - 66; }
  else { int k2 = k - 132; py = 1 + (k2 >> 1); px = (k2 & 1) ? 65 : 0; }
  int off = cc * CPLANE + ((b * 66 + py) * 66 + px) * 8;
  short8 z = {};
  *(short8*)(Xp0 + off) = z;
  *(short8*)(Xp1 + off) = z;
}

// ---------------------------------------------------------------------------
// Upsample (align-corners bilinear 32->64) + alpha*xm fuse -> bf16 c8 layout.
// Block: one (b,y) row x 64 x x 32 ch. Phase 3: lane = x -> each wave writes
// 1 KiB contiguous (one cchunk, 64 pixels). LDS reads broadcast (same c
// across the wave) -> conflict-free.
// ---------------------------------------------------------------------------
__global__ __launch_bounds__(256) void fuse_upsample_kernel(
    const float* __restrict__ xt, const float* __restrict__ xm,
    const float* __restrict__ alpha, unsigned short* __restrict__ Xp) {
  __shared__ float sm[32 * 66];        // xm tile [c][x], pad 66
  __shared__ float st[2 * 32 * 34];    // xt rows [h][c][x0..31], pad 34

  const int tid = threadIdx.x;
  const int ct = blockIdx.x & 15;          // channel tile (32 ch)
  const int y  = (blockIdx.x >> 4) & 63;
  const int b  = blockIdx.x >> 10;
  const int c0 = ct * 32;

  const float fy = y * (31.0f / 63.0f);
  const int y0 = (int)fy;
  const float wy = fy - (float)y0;
  const int y1 = min(y0 + 1, 31);

  // phase 1: xm tile, lane = x (coalesced 256B rows)
  {
    const int cb = (tid >> 6) * 8;
    const int xi = tid & 63;
#pragma unroll
    for (int j = 0; j < 8; ++j) {
      int c = cb + j;
      sm[c * 66 + xi] = xm[(((b << 9) + c0 + c) << 12) + (y << 6) + xi];
    }
  }
  // phase 2: xt rows y0,y1 (32 x-contiguous floats per (h,c) -> coalesced)
#pragma unroll
  for (int j = 0; j < 8; ++j) {
    int idx = j * 256 + tid;
    int xi = idx & 31, cc = (idx >> 5) & 31, h = idx >> 10;
    int yr = h ? y1 : y0;
    st[h * 1088 + cc * 34 + xi] =
        xt[(((b << 9) + c0 + cc) << 10) + (yr << 5) + xi];
  }
  __syncthreads();

  // phase 3: interpolate + fuse, write one c8 chunk per thread
  const float a = alpha[0];
  const int xo = tid & 63;
  const int cl = tid >> 6;             // local cchunk 0..3
  const float fx = xo * (31.0f / 63.0f);
  const int x0 = (int)fx;
  const float wx = fx - (float)x0;
  const int x1 = min(x0 + 1, 31);
  short8 ov;
#pragma unroll
  for (int j = 0; j < 8; ++j) {
    int c = cl * 8 + j;
    float t0 = st[c * 34 + x0], t1 = st[c * 34 + x1];
    float u0 = st[1088 + c * 34 + x0], u1 = st[1088 + c * 34 + x1];
    float top = t0 * (1.0f - wx) + t1 * wx;
    float bot = u0 * (1.0f - wx) + u1 * wx;
    float up = top * (1.0f - wy) + bot * wy;
    float val = up + a * sm[c * 66 + xo];
    ov[j] = (short)f2bf(val);
  }
  *(short8*)(Xp + ((c0 >> 3) + cl) * CPLANE +
             ((b * 66 + y + 1) * 66 + xo + 1) * 8) = ov;
}

// ---------------------------------------------------------------------------
// Repack weights OIHW fp32 -> [tap][cinchunk][cout][8] bf16 via LDS
// transpose. One block per output channel o; reads fully coalesced.
// ---------------------------------------------------------------------------
template <int COUT>
__global__ __launch_bounds__(256) void prep_w_kernel(
    const float* __restrict__ w, unsigned short* __restrict__ Wg) {
  __shared__ unsigned short l[4608];   // [tap][cin]
  const int o = blockIdx.x, t = threadIdx.x;
  const float* src = w + o * 4608;
#pragma unroll
  for (int j = 0; j < 18; ++j) {
    int idx = j * 256 + t;             // = i*9 + tap
    l[(idx % 9) * 512 + idx / 9] = f2bf(src[idx]);
  }
  __syncthreads();
#pragma unroll
  for (int tap = 0; tap < 9; ++tap) {
    // thread t owns cin pair (2t, 2t+1) -> chunk cc = t>>2, j = (2t)&7
    int cc = t >> 2;
    int off = ((tap * 64 + cc) * COUT + o) * 8 + ((2 * t) & 7);
    *(unsigned int*)(Wg + off) = *(const unsigned int*)(l + (tap << 9) + 2 * t);
  }
}

// ---------------------------------------------------------------------------
// Implicit-GEMM 3x3 conv + BN + ReLU.
// Input : c8 bf16 [64cc][8b][66][66][8] ; weights [9][64cc][COUT][8] bf16
// Block: 128 pixels x 128 couts, 4 waves (2x2), 64x64 each, 16x16x32 MFMA.
// BK=64 (72 K-steps). LDS k-major [8 kchunk][128 row][8 bf16] per tile ->
// conflict-free fragment reads. DMA: wave w owns kchunks {2w,2w+1}; each
// issue = 64 consecutive pixels/couts of one cchunk = 1 KiB contiguous.
// ---------------------------------------------------------------------------
template <int COUT, bool FINAL>
__global__ __launch_bounds__(256) void conv3x3_kernel(
    const unsigned short* __restrict__ Xp, const unsigned short* __restrict__ Wg,
    const float* __restrict__ gamma, const float* __restrict__ beta,
    const float* __restrict__ mean, const float* __restrict__ var,
    unsigned short* __restrict__ OutPad, float* __restrict__ OutF) {
  static_assert(COUT % 128 == 0, "");
  constexpr int NCT = COUT / 128;
  __shared__ unsigned short At[8192];  // 16 KB, [q][r][8]
  __shared__ unsigned short Bt[8192];

  const int tid = threadIdx.x;
  const int ptile = (int)blockIdx.x / NCT;
  const int ctile = (int)blockIdx.x % NCT;
  const int p0 = ptile * 128;          // 2 consecutive y-rows of one batch
  const int w = tid >> 6;
  const int lane = tid & 63;
  const int q0 = w * 2;

  // ---- staging: lane = pixel/cout within a row-half (contiguous 16B chunks)
  const int pb = p0 >> 12;
  const int yb = (p0 >> 6) & 63;
  const int apix0 = ((pb * 66 + yb + 1) * 66 + 1 + lane) * 8;  // h=0 row
  const int apix1 = apix0 + 66 * 8;                            // h=1 row
  const int brow0 = (ctile * 128 + lane) * 8;
  const int brow1 = brow0 + 64 * 8;

  unsigned short* Alds = At + q0 * 1024;   // [q][h*64+lane][8]
  unsigned short* Blds = Bt + q0 * 1024;

  // ---- fragment read setup
  const int fi = lane & 15;
  const int kc = lane >> 4;
  const int wm = w >> 1, wn = w & 1;
  const unsigned short* Abase = At + kc * 1024 + (wm * 64 + fi) * 8;
  const unsigned short* Bbase = Bt + kc * 1024 + (wn * 64 + fi) * 8;

  floatx4 acc[4][4] = {};

  for (int s = 0; s < 72; ++s) {
    const int tap = s >> 3;
    const int cg  = (s & 7) * 8;        // cchunk group base
    const int dy = tap / 3 - 1;
    const int dx = tap % 3 - 1;
    const int sh = (dy * 66 + dx) * 8;
    const int ab0 = (cg + q0) * CPLANE + sh;
    const int ab1 = ab0 + CPLANE;
    const int wb0 = ((tap * 64 + cg + q0) * COUT) * 8;
    const int wb1 = wb0 + COUT * 8;

    GLD(Xp + ab0 + apix0, Alds);
    GLD(Xp + ab0 + apix1, Alds + 512);
    GLD(Xp + ab1 + apix0, Alds + 1024);
    GLD(Xp + ab1 + apix1, Alds + 1536);
    GLD(Wg + wb0 + brow0, Blds);
    GLD(Wg + wb0 + brow1, Blds + 512);
    GLD(Wg + wb1 + brow0, Blds + 1024);
    GLD(Wg + wb1 + brow1, Blds + 1536);
    __syncthreads();   // drains vmcnt -> DMA complete

#pragma unroll
    for (int t = 0; t < 2; ++t) {
      short8 af[4], bfr[4];
#pragma unroll
      for (int mi = 0; mi < 4; ++mi)
        af[mi] = *(const short8*)(Abase + t * 4096 + mi * 128);
#pragma unroll
      for (int ni = 0; ni < 4; ++ni)
        bfr[ni] = *(const short8*)(Bbase + t * 4096 + ni * 128);
#pragma unroll
      for (int mi = 0; mi < 4; ++mi)
#pragma unroll
        for (int ni = 0; ni < 4; ++ni)
          acc[mi][ni] = __builtin_amdgcn_mfma_f32_16x16x32_bf16(
              af[mi], bfr[ni], acc[mi][ni], 0, 0, 0);
    }
    __syncthreads();   // protect LDS before next stage
  }

  // ---- epilogue: BN + ReLU
  // C/D layout: col = lane&15 (=cout), row = (lane>>4)*4 + reg (=pixel)
#pragma unroll
  for (int ni = 0; ni < 4; ++ni) {
    const int co = ctile * 128 + wn * 64 + ni * 16 + fi;
    const float sc = gamma[co] / sqrtf(var[co] + EPSV);
    const float sh2 = beta[co] - mean[co] * sc;
#pragma unroll
    for (int mi = 0; mi < 4; ++mi) {
      const int p = p0 + wm * 64 + mi * 16 + kc * 4;  // 4 consecutive pixels
      const int pbb = p >> 12;
      const int prem = p & 4095;
      if constexpr (FINAL) {
        floatx4 o;
#pragma unroll
        for (int r = 0; r < 4; ++r) o[r] = fmaxf(acc[mi][ni][r] * sc + sh2, 0.0f);
        *(floatx4*)(OutF + ((pbb * COUT + co) << 12) + prem) = o;  // NCHW fp32
      } else {
        const int py = prem >> 6, px = prem & 63;
        unsigned short* dst = OutPad + (co >> 3) * CPLANE +
            ((pbb * 66 + py + 1) * 66 + px + 1) * 8 + (co & 7);
#pragma unroll
        for (int r = 0; r < 4; ++r)
          dst[r * 8] = f2bf(fmaxf(acc[mi][ni][r] * sc + sh2, 0.0f));
      }
    }
  }
}

// ---------------------------------------------------------------------------
// workspace layout (bytes):
//   Xp0 : 0          .. 35684352   (64cc * 8*66*66 * 8 bf16)
//   Xp1 : 35684352   .. 71368704
//   Wg0 : 71368704   .. 76087296   (9*64*512*8 bf16)
//   Wg1 : 76087296   .. 78446592   (9*64*256*8 bf16)
// ---------------------------------------------------------------------------
extern "C" void kernel_launch(void* const* d_in, const int* in_sizes, int n_in,
                              void* d_out, int out_size, void* d_ws, size_t ws_size,
                              hipStream_t stream) {
  const float* xt    = (const float*)d_in[0];
  const float* xm    = (const float*)d_in[1];
  const float* alpha = (const float*)d_in[3];
  const float* w0    = (const float*)d_in[4];
  const float* g0    = (const float*)d_in[5];
  const float* b0    = (const float*)d_in[6];
  const float* m0    = (const float*)d_in[7];
  const float* v0    = (const float*)d_in[8];
  const float* w1    = (const float*)d_in[9];
  const float* g1    = (const float*)d_in[10];
  const float* b1    = (const float*)d_in[11];
  const float* m1    = (const float*)d_in[12];
  const float* v1    = (const float*)d_in[13];
  float* out = (float*)d_out;

  char* ws = (char*)d_ws;
  unsigned short* Xp0 = (unsigned short*)(ws);
  unsigned short* Xp1 = (unsigned short*)(ws + 35684352);
  unsigned short* Wg0 = (unsigned short*)(ws + 2 * 35684352);
  unsigned short* Wg1 = (unsigned short*)(ws + 2 * 35684352 + 4718592);

  border_zero_kernel<<<520, 256, 0, stream>>>(Xp0, Xp1);
  prep_w_kernel<512><<<512, 256, 0, stream>>>(w0, Wg0);
  prep_w_kernel<256><<<256, 256, 0, stream>>>(w1, Wg1);
  fuse_upsample_kernel<<<8192, 256, 0, stream>>>(xt, xm, alpha, Xp0);
  conv3x3_kernel<512, false><<<1024, 256, 0, stream>>>(Xp0, Wg0, g0, b0, m0, v0, Xp1, nullptr);
  conv3x3_kernel<256, true><<<512, 256, 0, stream>>>(Xp1, Wg1, g1, b1, m1, v1, nullptr, out);
}

// Round 4
// 482.670 us; speedup vs baseline: 1.6181x; 1.1762x over previous
//
#include <hip/hip_runtime.h>
#include <stdint.h>

#define EPSV 1e-5f

// c8-chunked activation layout: elem = cc*278784 + ((b*66+y)*66+x)*8 + (c&7)
#define CPLANE 278784   // 8*66*66*8 elems per channel-chunk plane

using floatx4 = __attribute__((ext_vector_type(4))) float;
using short8  = __attribute__((ext_vector_type(8))) short;

// async global->LDS 16B DMA: data lands at ldsbase + lane*16
#define GLD(gp, lp) __builtin_amdgcn_global_load_lds( \
    (const __attribute__((address_space(1))) void*)(gp), \
    (__attribute__((address_space(3))) void*)(lp), 16, 0, 0)

__device__ __forceinline__ unsigned short f2bf(float f) {
  union { float f; unsigned int u; } x; x.f = f;
  unsigned int r = x.u + 0x7fffu + ((x.u >> 16) & 1u);  // RNE
  return (unsigned short)(r >> 16);
}

// ---------------------------------------------------------------------------
// Zero the halo border of both padded c8 buffers (2.13 MB each).
// ---------------------------------------------------------------------------
__global__ __launch_bounds__(256) void border_zero_kernel(
    unsigned short* __restrict__ Xp0, unsigned short* __restrict__ Xp1) {
  int idx = blockIdx.x * 256 + threadIdx.x;   // 520*256 = 133120 = 8*64*260
  int k = idx % 260;
  int rest = idx / 260;
  int cc = rest & 63;
  int b = rest >> 6;
  int py, px;
  if (k < 66)       { py = 0;  px = k; }
  else if (k < 132) { py = 65; px = k - 66; }
  else { int k2 = k - 132; py = 1 + (k2 >> 1); px = (k2 & 1) ? 65 : 0; }
  int off = cc * CPLANE + ((b * 66 + py) * 66 + px) * 8;
  short8 z = {};
  *(short8*)(Xp0 + off) = z;
  *(short8*)(Xp1 + off) = z;
}

// ---------------------------------------------------------------------------
// Upsample (align-corners bilinear 32->64) + alpha*xm fuse -> bf16 c8 layout.
// ---------------------------------------------------------------------------
__global__ __launch_bounds__(256) void fuse_upsample_kernel(
    const float* __restrict__ xt, const float* __restrict__ xm,
    const float* __restrict__ alpha, unsigned short* __restrict__ Xp) {
  __shared__ float sm[32 * 66];        // xm tile [c][x], pad 66
  __shared__ float st[2 * 32 * 34];    // xt rows [h][c][x0..31], pad 34

  const int tid = threadIdx.x;
  const int ct = blockIdx.x & 15;          // channel tile (32 ch)
  const int y  = (blockIdx.x >> 4) & 63;
  const int b  = blockIdx.x >> 10;
  const int c0 = ct * 32;

  const float fy = y * (31.0f / 63.0f);
  const int y0 = (int)fy;
  const float wy = fy - (float)y0;
  const int y1 = min(y0 + 1, 31);

  // phase 1: xm tile, lane = x (coalesced 256B rows)
  {
    const int cb = (tid >> 6) * 8;
    const int xi = tid & 63;
#pragma unroll
    for (int j = 0; j < 8; ++j) {
      int c = cb + j;
      sm[c * 66 + xi] = xm[(((b << 9) + c0 + c) << 12) + (y << 6) + xi];
    }
  }
  // phase 2: xt rows y0,y1 (32 x-contiguous floats per (h,c) -> coalesced)
#pragma unroll
  for (int j = 0; j < 8; ++j) {
    int idx = j * 256 + tid;
    int xi = idx & 31, cc = (idx >> 5) & 31, h = idx >> 10;
    int yr = h ? y1 : y0;
    st[h * 1088 + cc * 34 + xi] =
        xt[(((b << 9) + c0 + cc) << 10) + (yr << 5) + xi];
  }
  __syncthreads();

  // phase 3: interpolate + fuse, write one c8 chunk per thread
  const float a = alpha[0];
  const int xo = tid & 63;
  const int cl = tid >> 6;             // local cchunk 0..3
  const float fx = xo * (31.0f / 63.0f);
  const int x0 = (int)fx;
  const float wx = fx - (float)x0;
  const int x1 = min(x0 + 1, 31);
  short8 ov;
#pragma unroll
  for (int j = 0; j < 8; ++j) {
    int c = cl * 8 + j;
    float t0 = st[c * 34 + x0], t1 = st[c * 34 + x1];
    float u0 = st[1088 + c * 34 + x0], u1 = st[1088 + c * 34 + x1];
    float top = t0 * (1.0f - wx) + t1 * wx;
    float bot = u0 * (1.0f - wx) + u1 * wx;
    float up = top * (1.0f - wy) + bot * wy;
    float val = up + a * sm[c * 66 + xo];
    ov[j] = (short)f2bf(val);
  }
  *(short8*)(Xp + ((c0 >> 3) + cl) * CPLANE +
             ((b * 66 + y + 1) * 66 + xo + 1) * 8) = ov;
}

// ---------------------------------------------------------------------------
// Repack weights OIHW fp32 -> [tap][cinchunk][cout][8] bf16 via LDS transpose.
// ---------------------------------------------------------------------------
template <int COUT>
__global__ __launch_bounds__(256) void prep_w_kernel(
    const float* __restrict__ w, unsigned short* __restrict__ Wg) {
  __shared__ unsigned short l[4608];   // [tap][cin]
  const int o = blockIdx.x, t = threadIdx.x;
  const float* src = w + o * 4608;
#pragma unroll
  for (int j = 0; j < 18; ++j) {
    int idx = j * 256 + t;             // = i*9 + tap
    l[(idx % 9) * 512 + idx / 9] = f2bf(src[idx]);
  }
  __syncthreads();
#pragma unroll
  for (int tap = 0; tap < 9; ++tap) {
    int cc = t >> 2;
    int off = ((tap * 64 + cc) * COUT + o) * 8 + ((2 * t) & 7);
    *(unsigned int*)(Wg + off) = *(const unsigned int*)(l + (tap << 9) + 2 * t);
  }
}

// ---------------------------------------------------------------------------
// Implicit-GEMM 3x3 conv + BN + ReLU, A-resident / B-prefetch K-loop.
// Input : c8 bf16 [64cc][8b][66][66][8] ; weights [9][64cc][COUT][8] bf16
// Block: 128 pixels x CTILE couts, 4 waves (2x2), wave = 64px x CTILE/2.
// Outer loop: 8 c-groups (64ch). Per c-group: stage A = 4 input rows x 66 px
// (33 KiB, halo included) ONCE; inner 9 taps read shifted windows. B tile
// [8kc][CTILE][8] double-buffered; next tap's B DMA issued BEFORE current
// tap's MFMAs -> the barrier drain overlaps the compute phase.
// ---------------------------------------------------------------------------
template <int COUT, int CTILE, bool FINAL>
__global__ __launch_bounds__(256) void conv3x3_kernel(
    const unsigned short* __restrict__ Xp, const unsigned short* __restrict__ Wg,
    const float* __restrict__ gamma, const float* __restrict__ beta,
    const float* __restrict__ mean, const float* __restrict__ var,
    unsigned short* __restrict__ OutPad, float* __restrict__ OutF) {
  constexpr int NCT = COUT / CTILE;
  constexpr int NI  = CTILE / 32;          // n-subtiles per wave
  __shared__ unsigned short Abuf[16896];   // [kc 8][row 4][x 66][8] = 33 KiB
  __shared__ unsigned short Bbuf0[CTILE * 64];  // [kc 8][CTILE][8]
  __shared__ unsigned short Bbuf1[CTILE * 64];

  const int tid = threadIdx.x;
  const int ptile = (int)blockIdx.x / NCT;
  const int ctile = (int)blockIdx.x % NCT;
  const int p0 = ptile * 128;          // 2 consecutive y-rows of one batch
  const int w = tid >> 6;
  const int lane = tid & 63;

  const int pb = p0 >> 12;             // batch
  const int yb = (p0 >> 6) & 63;       // first input padded row (dy=-1)
  const int arowg = ((pb * 66 + yb) * 66) * 8;   // global elem offset of row 0

  // ---- fragment read setup
  const int fi = lane & 15;
  const int kc = lane >> 4;
  const int wm = w >> 1, wn = w & 1;
  const int aLane = kc * 2112 + (wm + 1) * 528 + (fi + 1) * 8;
  const int bLane = kc * CTILE * 8 + (wn * (CTILE / 2) + fi) * 8;

  floatx4 acc[4][NI] = {};

  // ---- staging lambdas (wave w owns kchunks {2w, 2w+1})
  auto stageA = [&](int cg) {
#pragma unroll
    for (int kk = 0; kk < 2; ++kk) {
      const int kc2 = 2 * w + kk;
      const unsigned short* g = Xp + (cg * 8 + kc2) * CPLANE + arowg + lane * 8;
      unsigned short* d = Abuf + kc2 * 2112;
#pragma unroll
      for (int rr = 0; rr < 4; ++rr) {
        GLD(g + rr * 528,      d + rr * 528);        // x chunks 0..63
        GLD(g + rr * 528 + 16, d + rr * 528 + 16);   // x chunks 2..65 (overlap)
      }
    }
  };
  auto stageB = [&](int tap, int cg, unsigned short* dst) {
#pragma unroll
    for (int kk = 0; kk < 2; ++kk) {
      const int kc2 = 2 * w + kk;
      const unsigned short* g =
          Wg + ((tap * 64 + cg * 8 + kc2) * COUT + ctile * CTILE + lane) * 8;
#pragma unroll
      for (int half = 0; half < CTILE / 64; ++half)
        GLD(g + half * 64 * 8, dst + (kc2 * CTILE + half * 64) * 8);
    }
  };
  auto compute = [&](const unsigned short* Bsel, int dy, int dx) {
#pragma unroll
    for (int t = 0; t < 2; ++t) {
      short8 af[4];
#pragma unroll
      for (int mi = 0; mi < 4; ++mi)
        af[mi] = *(const short8*)(Abuf + aLane + t * 8448 + dy * 528 +
                                  (mi * 16 + dx) * 8);
      short8 bfr[NI];
#pragma unroll
      for (int ni = 0; ni < NI; ++ni)
        bfr[ni] = *(const short8*)(Bsel + bLane + t * CTILE * 32 + ni * 128);
#pragma unroll
      for (int mi = 0; mi < 4; ++mi)
#pragma unroll
        for (int ni = 0; ni < NI; ++ni)
          acc[mi][ni] = __builtin_amdgcn_mfma_f32_16x16x32_bf16(
              af[mi], bfr[ni], acc[mi][ni], 0, 0, 0);
    }
  };

  // ---- main loop
  int buf = 0;
  stageA(0);
  stageB(0, 0, Bbuf0);
  __syncthreads();
  for (int cg = 0; cg < 8; ++cg) {
#pragma unroll
    for (int tap = 0; tap < 9; ++tap) {
      unsigned short* cur = buf ? Bbuf1 : Bbuf0;
      unsigned short* nxt = buf ? Bbuf0 : Bbuf1;
      if (tap < 8)      stageB(tap + 1, cg, nxt);      // prefetch next tap
      else if (cg < 7)  stageB(0, cg + 1, nxt);        // prefetch next c-group
      compute(cur, tap / 3 - 1, tap % 3 - 1);
      __syncthreads();   // drains prefetch DMA (flew during MFMAs)
      buf ^= 1;
    }
    if (cg < 7) {
      stageA(cg + 1);    // A region free: all taps of cg done
      __syncthreads();
    }
  }

  // ---- epilogue: BN + ReLU
  // C/D layout: col = lane&15 (=cout), row = (lane>>4)*4 + reg (=pixel)
#pragma unroll
  for (int ni = 0; ni < NI; ++ni) {
    const int co = ctile * CTILE + wn * (CTILE / 2) + ni * 16 + fi;
    const float sc = gamma[co] / sqrtf(var[co] + EPSV);
    const float sh2 = beta[co] - mean[co] * sc;
#pragma unroll
    for (int mi = 0; mi < 4; ++mi) {
      const int p = p0 + wm * 64 + mi * 16 + kc * 4;  // 4 consecutive pixels
      const int pbb = p >> 12;
      const int prem = p & 4095;
      if constexpr (FINAL) {
        floatx4 o;
#pragma unroll
        for (int r = 0; r < 4; ++r) o[r] = fmaxf(acc[mi][ni][r] * sc + sh2, 0.0f);
        *(floatx4*)(OutF + ((pbb * COUT + co) << 12) + prem) = o;  // NCHW fp32
      } else {
        const int py = prem >> 6, px = prem & 63;
        unsigned short* dst = OutPad + (co >> 3) * CPLANE +
            ((pbb * 66 + py + 1) * 66 + px + 1) * 8 + (co & 7);
#pragma unroll
        for (int r = 0; r < 4; ++r)
          dst[r * 8] = f2bf(fmaxf(acc[mi][ni][r] * sc + sh2, 0.0f));
      }
    }
  }
}

// ---------------------------------------------------------------------------
// workspace layout (bytes):
//   Xp0 : 0          .. 35684352   (64cc * 8*66*66 * 8 bf16)
//   Xp1 : 35684352   .. 71368704
//   Wg0 : 71368704   .. 76087296   (9*64*512*8 bf16)
//   Wg1 : 76087296   .. 78446592   (9*64*256*8 bf16)
// ---------------------------------------------------------------------------
extern "C" void kernel_launch(void* const* d_in, const int* in_sizes, int n_in,
                              void* d_out, int out_size, void* d_ws, size_t ws_size,
                              hipStream_t stream) {
  const float* xt    = (const float*)d_in[0];
  const float* xm    = (const float*)d_in[1];
  const float* alpha = (const float*)d_in[3];
  const float* w0    = (const float*)d_in[4];
  const float* g0    = (const float*)d_in[5];
  const float* b0    = (const float*)d_in[6];
  const float* m0    = (const float*)d_in[7];
  const float* v0    = (const float*)d_in[8];
  const float* w1    = (const float*)d_in[9];
  const float* g1    = (const float*)d_in[10];
  const float* b1    = (const float*)d_in[11];
  const float* m1    = (const float*)d_in[12];
  const float* v1    = (const float*)d_in[13];
  float* out = (float*)d_out;

  char* ws = (char*)d_ws;
  unsigned short* Xp0 = (unsigned short*)(ws);
  unsigned short* Xp1 = (unsigned short*)(ws + 35684352);
  unsigned short* Wg0 = (unsigned short*)(ws + 2 * 35684352);
  unsigned short* Wg1 = (unsigned short*)(ws + 2 * 35684352 + 4718592);

  border_zero_kernel<<<520, 256, 0, stream>>>(Xp0, Xp1);
  prep_w_kernel<512><<<512, 256, 0, stream>>>(w0, Wg0);
  prep_w_kernel<256><<<256, 256, 0, stream>>>(w1, Wg1);
  fuse_upsample_kernel<<<8192, 256, 0, stream>>>(xt, xm, alpha, Xp0);
  conv3x3_kernel<512, 128, false><<<1024, 256, 0, stream>>>(Xp0, Wg0, g0, b0, m0, v0, Xp1, nullptr);
  conv3x3_kernel<256, 64, true><<<1024, 256, 0, stream>>>(Xp1, Wg1, g1, b1, m1, v1, nullptr, out);
}